// Round 9
// baseline (108.533 us; speedup 1.0000x reference)
//
#include <hip/hip_runtime.h>
#include <hip/hip_bf16.h>

typedef __attribute__((ext_vector_type(8))) short s8v;            // 8 x bf16
typedef __attribute__((ext_vector_type(4))) float f4v;            // 4 x f32

__device__ __forceinline__ short f2bf(float f) {
    __hip_bfloat16 h = __float2bfloat16(f);
    union { __hip_bfloat16 h; short s; } u{h};
    return u.s;
}
__device__ __forceinline__ float bf2f(unsigned short v) {
    union { unsigned u; float f; } x; x.u = ((unsigned)v) << 16; return x.f;
}
__device__ __forceinline__ unsigned packbf(float a, float b) {
    return (unsigned)(unsigned short)f2bf(a) | ((unsigned)(unsigned short)f2bf(b) << 16);
}

// ---------------------------------------------------------------------------
// prep: blocks [0,40) pack weights (W2 packs pre-scaled by g1: W2' = g1 o W2)
// into MFMA fragment order; blocks 40/41 compute LN1-folding vectors
// s2[c] = colsum(bf16(W2')), bW2[c] = b1 @ W2.
// ---------------------------------------------------------------------------
__global__ void prep_kernel(const float* __restrict__ w1c, const float* __restrict__ w2c,
                            const float* __restrict__ g1c, const float* __restrict__ b1c,
                            const float* __restrict__ w1f, const float* __restrict__ w2f,
                            const float* __restrict__ g1f, const float* __restrict__ b1f,
                            short* __restrict__ p1c, short* __restrict__ p2c,
                            short* __restrict__ p1f, short* __restrict__ p2f,
                            float* __restrict__ s2c, float* __restrict__ bwc,
                            float* __restrict__ s2f, float* __restrict__ bwf)
{
    int b = blockIdx.x, t = threadIdx.x;
    if (b >= 40) {                       // folding vectors
        if (t >= 128) return;
        const float* W  = (b == 40) ? w2c : w2f;
        const float* g1 = (b == 40) ? g1c : g1f;
        const float* b1 = (b == 40) ? b1c : b1f;
        float* s2 = (b == 40) ? s2c : s2f;
        float* bw = (b == 40) ? bwc : bwf;
        float s = 0.f, w2sum = 0.f;
        for (int k = 0; k < 128; ++k) {
            float wv = W[k * 128 + t];
            s     += bf2f((unsigned short)f2bf(g1[k] * wv));  // match MFMA rounding
            w2sum += b1[k] * wv;
        }
        s2[t] = s; bw[t] = w2sum;
        return;
    }
    int id = b * 256 + t;                 // 40*256 = 160 frags * 64 lanes
    int f  = id >> 6, l = id & 63;
    const float* W; const float* g1 = nullptr; short* P; int fl;
    if      (f < 64)  { W = w1c; P = p1c; fl = f; }                   // K=256
    else if (f < 96)  { W = w2c; P = p2c; fl = f - 64;  g1 = g1c; }   // scaled
    else if (f < 128) { W = w1f; P = p1f; fl = f - 96; }
    else              { W = w2f; P = p2f; fl = f - 128; g1 = g1f; }   // scaled
    int g = l >> 4, c = l & 15;
    int ks = fl >> 3, n = fl & 7;
    s8v o;
    #pragma unroll
    for (int e = 0; e < 8; ++e) {
        int k = ks*32 + g*8 + e;
        float v = W[k * 128 + n*16 + c];
        if (g1) v *= g1[k];
        o[e] = f2bf(v);
    }
    *(s8v*)(P + ((fl*64 + l) << 3)) = o;
}

// ---------------------------------------------------------------------------
// Monolithic swapped-orientation fused MLP (R8; used for coarse + fallback).
// ---------------------------------------------------------------------------
template<int K1, bool FINE>
__global__ __launch_bounds__(256, 4)
void mlp_mfma(const float* __restrict__ X,
              const short* __restrict__ WpA,     // packed W1 (A-operand)
              const short* __restrict__ WpB,     // packed W2' (A-operand)
              const float* __restrict__ s2v, const float* __restrict__ bwv,
              const float* __restrict__ g2v, const float* __restrict__ b2v,
              float* __restrict__ outF,
              unsigned short* __restrict__ outB,
              const int* __restrict__ winner,
              const unsigned short* __restrict__ fcB,
              const int* __restrict__ nr, const int* __restrict__ nc,
              int* __restrict__ win, int nWinBlocks)
{
    if (blockIdx.x < (unsigned)nWinBlocks) {
        int i = blockIdx.x * 256 + threadIdx.x;
        atomicMax(&win[nr[i] * 32 + nc[i]], i);
        return;
    }
    const int bid  = blockIdx.x - nWinBlocks;
    const int t    = threadIdx.x;
    const int wave = t >> 6, lane = t & 63;
    const int G = lane >> 4, n16 = lane & 15;
    const int row = bid * 64 + wave * 16 + n16;
    const size_t rowK = (size_t)row * K1;

    int wv = 0;
    if constexpr (FINE) wv = winner[row];

    f4v acc1[8];
    #pragma unroll
    for (int mt = 0; mt < 8; ++mt) acc1[mt] = (f4v){0.f, 0.f, 0.f, 0.f};

    const short* wpa = WpA + (lane << 3);
    const float* pX  = X + rowK + G*8;
    #pragma unroll
    for (int kb = 0; kb < K1/32; kb += 4) {
        float4 aPf[4][2];
        #pragma unroll
        for (int k2 = 0; k2 < 4; ++k2) {
            aPf[k2][0] = *(const float4*)(pX + (kb + k2)*32);
            aPf[k2][1] = *(const float4*)(pX + (kb + k2)*32 + 4);
        }
        #pragma unroll
        for (int k2 = 0; k2 < 4; ++k2) {
            const int ks = kb + k2;
            s8v wfr[8];
            #pragma unroll
            for (int mt = 0; mt < 8; ++mt)
                wfr[mt] = *(const s8v*)(wpa + ((ks*8 + mt) << 9));
            s8v xf;
            xf[0] = f2bf(aPf[k2][0].x); xf[1] = f2bf(aPf[k2][0].y);
            xf[2] = f2bf(aPf[k2][0].z); xf[3] = f2bf(aPf[k2][0].w);
            xf[4] = f2bf(aPf[k2][1].x); xf[5] = f2bf(aPf[k2][1].y);
            xf[6] = f2bf(aPf[k2][1].z); xf[7] = f2bf(aPf[k2][1].w);
            #pragma unroll
            for (int mt = 0; mt < 8; ++mt)
                acc1[mt] = __builtin_amdgcn_mfma_f32_16x16x32_bf16(wfr[mt], xf, acc1[mt], 0, 0, 0);
        }
    }

    float sm = 0.f, sq = 0.f;
    #pragma unroll
    for (int mt = 0; mt < 8; ++mt)
        #pragma unroll
        for (int j = 0; j < 4; ++j) { float v = acc1[mt][j]; sm += v; sq += v*v; }
    sm += __shfl_xor(sm, 16, 64); sm += __shfl_xor(sm, 32, 64);
    sq += __shfl_xor(sq, 16, 64); sq += __shfl_xor(sq, 32, 64);
    const float mean1 = sm * (1.f/128.f);
    const float rstd1 = rsqrtf(sq * (1.f/128.f) - mean1*mean1 + 1e-5f);

    unsigned pk[8][2];
    #pragma unroll
    for (int mt = 0; mt < 8; ++mt) {
        pk[mt][0] = packbf(acc1[mt][0], acc1[mt][1]);
        pk[mt][1] = packbf(acc1[mt][2], acc1[mt][3]);
    }

    f4v acc2[8];
    #pragma unroll
    for (int mt = 0; mt < 8; ++mt) acc2[mt] = (f4v){0.f, 0.f, 0.f, 0.f};

    const short* wpb = WpB + (lane << 3);
    const int src0 = ((G & 1) << 5) + n16;
    const int src1 = src0 + 16;
    const bool hiG = (G >= 2);
    #pragma unroll
    for (int ks = 0; ks < 4; ++ks) {
        int r00 = __shfl((int)pk[2*ks][0],   src0, 64);
        int r01 = __shfl((int)pk[2*ks][1],   src0, 64);
        int r02 = __shfl((int)pk[2*ks][0],   src1, 64);
        int r03 = __shfl((int)pk[2*ks][1],   src1, 64);
        int r10 = __shfl((int)pk[2*ks+1][0], src0, 64);
        int r11 = __shfl((int)pk[2*ks+1][1], src0, 64);
        int r12 = __shfl((int)pk[2*ks+1][0], src1, 64);
        int r13 = __shfl((int)pk[2*ks+1][1], src1, 64);
        union { int u[4]; s8v v; } hb;
        hb.u[0] = hiG ? r10 : r00; hb.u[1] = hiG ? r11 : r01;
        hb.u[2] = hiG ? r12 : r02; hb.u[3] = hiG ? r13 : r03;
        s8v wfr[8];
        #pragma unroll
        for (int mt = 0; mt < 8; ++mt)
            wfr[mt] = *(const s8v*)(wpb + ((ks*8 + mt) << 9));
        #pragma unroll
        for (int mt = 0; mt < 8; ++mt)
            acc2[mt] = __builtin_amdgcn_mfma_f32_16x16x32_bf16(wfr[mt], hb.v, acc2[mt], 0, 0, 0);
    }

    float h2[8][4];
    float sm2 = 0.f, sq2 = 0.f;
    #pragma unroll
    for (int mt = 0; mt < 8; ++mt) {
        const int col = mt*16 + G*4;
        f4v s2l = *(const f4v*)&s2v[col];
        f4v bwl = *(const f4v*)&bwv[col];
        #pragma unroll
        for (int j = 0; j < 4; ++j) {
            float v = rstd1 * (acc2[mt][j] - mean1 * s2l[j]) + bwl[j];
            h2[mt][j] = v; sm2 += v; sq2 += v*v;
        }
    }
    sm2 += __shfl_xor(sm2, 16, 64); sm2 += __shfl_xor(sm2, 32, 64);
    sq2 += __shfl_xor(sq2, 16, 64); sq2 += __shfl_xor(sq2, 32, 64);
    const float mean2 = sm2 * (1.f/128.f);
    const float rstd2 = rsqrtf(sq2 * (1.f/128.f) - mean2*mean2 + 1e-5f);

    if constexpr (FINE) {
        ushort4 gv[8];
        const bool hasw = (wv >= 0);
        const size_t src = (size_t)(wv & 32767) * 128;
        if (hasw) {
            #pragma unroll
            for (int mt = 0; mt < 8; ++mt)
                gv[mt] = *(const ushort4*)(fcB + src + mt*16 + G*4);
        }
        #pragma unroll
        for (int mt = 0; mt < 8; ++mt) {
            const int col = mt*16 + G*4;
            f4v g2l = *(const f4v*)&g2v[col];
            f4v b2l = *(const f4v*)&b2v[col];
            float z0 = fmaxf((h2[mt][0]-mean2)*rstd2*g2l[0] + b2l[0], 0.f);
            float z1 = fmaxf((h2[mt][1]-mean2)*rstd2*g2l[1] + b2l[1], 0.f);
            float z2 = fmaxf((h2[mt][2]-mean2)*rstd2*g2l[2] + b2l[2], 0.f);
            float z3 = fmaxf((h2[mt][3]-mean2)*rstd2*g2l[3] + b2l[3], 0.f);
            if (hasw) {
                z0 += bf2f(gv[mt].x); z1 += bf2f(gv[mt].y);
                z2 += bf2f(gv[mt].z); z3 += bf2f(gv[mt].w);
            }
            float4 o; o.x = z0; o.y = z1; o.z = z2; o.w = z3;
            *(float4*)(outF + (size_t)row * 128 + col) = o;
        }
    } else {
        #pragma unroll
        for (int mt = 0; mt < 8; ++mt) {
            const int col = mt*16 + G*4;
            f4v g2l = *(const f4v*)&g2v[col];
            f4v b2l = *(const f4v*)&b2v[col];
            ushort4 o;
            o.x = (unsigned short)f2bf(fmaxf((h2[mt][0]-mean2)*rstd2*g2l[0] + b2l[0], 0.f));
            o.y = (unsigned short)f2bf(fmaxf((h2[mt][1]-mean2)*rstd2*g2l[1] + b2l[1], 0.f));
            o.z = (unsigned short)f2bf(fmaxf((h2[mt][2]-mean2)*rstd2*g2l[2] + b2l[2], 0.f));
            o.w = (unsigned short)f2bf(fmaxf((h2[mt][3]-mean2)*rstd2*g2l[3] + b2l[3], 0.f));
            *(ushort4*)(outB + (size_t)row * 128 + col) = o;
        }
    }
}

// ---------------------------------------------------------------------------
// ABLATION SPLIT, phase 1: H1raw = X @ W1 (swapped orient) + LN1 stats.
// Stores H1 bf16 row-major [row][128] + per-row (mean1, rstd1).
// ---------------------------------------------------------------------------
__global__ __launch_bounds__(256, 4)
void fine_l1(const float* __restrict__ X, const short* __restrict__ WpA,
             unsigned short* __restrict__ H1, float2* __restrict__ stats)
{
    const int t = threadIdx.x;
    const int wave = t >> 6, lane = t & 63;
    const int G = lane >> 4, n16 = lane & 15;
    const int row = blockIdx.x * 64 + wave * 16 + n16;

    float4 aPf[4][2];
    const float* pX = X + (size_t)row * 128 + G*8;
    #pragma unroll
    for (int ks = 0; ks < 4; ++ks) {
        aPf[ks][0] = *(const float4*)(pX + ks*32);
        aPf[ks][1] = *(const float4*)(pX + ks*32 + 4);
    }

    f4v acc1[8];
    #pragma unroll
    for (int mt = 0; mt < 8; ++mt) acc1[mt] = (f4v){0.f, 0.f, 0.f, 0.f};

    const short* wpa = WpA + (lane << 3);
    #pragma unroll
    for (int ks = 0; ks < 4; ++ks) {
        s8v wfr[8];
        #pragma unroll
        for (int mt = 0; mt < 8; ++mt)
            wfr[mt] = *(const s8v*)(wpa + ((ks*8 + mt) << 9));
        s8v xf;
        xf[0] = f2bf(aPf[ks][0].x); xf[1] = f2bf(aPf[ks][0].y);
        xf[2] = f2bf(aPf[ks][0].z); xf[3] = f2bf(aPf[ks][0].w);
        xf[4] = f2bf(aPf[ks][1].x); xf[5] = f2bf(aPf[ks][1].y);
        xf[6] = f2bf(aPf[ks][1].z); xf[7] = f2bf(aPf[ks][1].w);
        #pragma unroll
        for (int mt = 0; mt < 8; ++mt)
            acc1[mt] = __builtin_amdgcn_mfma_f32_16x16x32_bf16(wfr[mt], xf, acc1[mt], 0, 0, 0);
    }

    float sm = 0.f, sq = 0.f;
    #pragma unroll
    for (int mt = 0; mt < 8; ++mt)
        #pragma unroll
        for (int j = 0; j < 4; ++j) { float v = acc1[mt][j]; sm += v; sq += v*v; }
    sm += __shfl_xor(sm, 16, 64); sm += __shfl_xor(sm, 32, 64);
    sq += __shfl_xor(sq, 16, 64); sq += __shfl_xor(sq, 32, 64);
    const float mean1 = sm * (1.f/128.f);
    const float rstd1 = rsqrtf(sq * (1.f/128.f) - mean1*mean1 + 1e-5f);

    unsigned short* hp = H1 + (size_t)row * 128 + G*4;
    #pragma unroll
    for (int mt = 0; mt < 8; ++mt) {
        uint2 o;
        o.x = packbf(acc1[mt][0], acc1[mt][1]);
        o.y = packbf(acc1[mt][2], acc1[mt][3]);
        *(uint2*)(hp + mt*16) = o;
    }
    if (lane < 16) stats[row] = make_float2(mean1, rstd1);
}

// ---------------------------------------------------------------------------
// ABLATION SPLIT, phase 2: H2 = W2'^T @ H1^T with folded LN1; LN2 + ReLU +
// winner gather-add; store f32 out. B-frags are contiguous 16B loads of H1.
// ---------------------------------------------------------------------------
__global__ __launch_bounds__(256, 4)
void fine_l2(const unsigned short* __restrict__ H1, const float2* __restrict__ stats,
             const short* __restrict__ WpB,
             const float* __restrict__ s2v, const float* __restrict__ bwv,
             const float* __restrict__ g2v, const float* __restrict__ b2v,
             const int* __restrict__ winner, const unsigned short* __restrict__ fcB,
             float* __restrict__ out)
{
    const int t = threadIdx.x;
    const int wave = t >> 6, lane = t & 63;
    const int G = lane >> 4, n16 = lane & 15;
    const int row = blockIdx.x * 64 + wave * 16 + n16;

    const int wv = winner[row];
    const float2 st = stats[row];

    // gather prefetch FIRST (independent of everything below)
    ushort4 gv[8];
    const bool hasw = (wv >= 0);
    const size_t src = (size_t)(wv & 32767) * 128;
    if (hasw) {
        #pragma unroll
        for (int mt = 0; mt < 8; ++mt)
            gv[mt] = *(const ushort4*)(fcB + src + mt*16 + G*4);
    }

    // B-fragments: contiguous 16B per ks
    s8v hb[4];
    const unsigned short* hp = H1 + (size_t)row * 128 + G*8;
    #pragma unroll
    for (int ks = 0; ks < 4; ++ks)
        hb[ks] = *(const s8v*)(hp + ks*32);

    f4v acc2[8];
    #pragma unroll
    for (int mt = 0; mt < 8; ++mt) acc2[mt] = (f4v){0.f, 0.f, 0.f, 0.f};

    const short* wpb = WpB + (lane << 3);
    #pragma unroll
    for (int ks = 0; ks < 4; ++ks) {
        s8v wfr[8];
        #pragma unroll
        for (int mt = 0; mt < 8; ++mt)
            wfr[mt] = *(const s8v*)(wpb + ((ks*8 + mt) << 9));
        #pragma unroll
        for (int mt = 0; mt < 8; ++mt)
            acc2[mt] = __builtin_amdgcn_mfma_f32_16x16x32_bf16(wfr[mt], hb[ks], acc2[mt], 0, 0, 0);
    }

    float h2[8][4];
    float sm2 = 0.f, sq2 = 0.f;
    #pragma unroll
    for (int mt = 0; mt < 8; ++mt) {
        const int col = mt*16 + G*4;
        f4v s2l = *(const f4v*)&s2v[col];
        f4v bwl = *(const f4v*)&bwv[col];
        #pragma unroll
        for (int j = 0; j < 4; ++j) {
            float v = st.y * (acc2[mt][j] - st.x * s2l[j]) + bwl[j];
            h2[mt][j] = v; sm2 += v; sq2 += v*v;
        }
    }
    sm2 += __shfl_xor(sm2, 16, 64); sm2 += __shfl_xor(sm2, 32, 64);
    sq2 += __shfl_xor(sq2, 16, 64); sq2 += __shfl_xor(sq2, 32, 64);
    const float mean2 = sm2 * (1.f/128.f);
    const float rstd2 = rsqrtf(sq2 * (1.f/128.f) - mean2*mean2 + 1e-5f);

    #pragma unroll
    for (int mt = 0; mt < 8; ++mt) {
        const int col = mt*16 + G*4;
        f4v g2l = *(const f4v*)&g2v[col];
        f4v b2l = *(const f4v*)&b2v[col];
        float z0 = fmaxf((h2[mt][0]-mean2)*rstd2*g2l[0] + b2l[0], 0.f);
        float z1 = fmaxf((h2[mt][1]-mean2)*rstd2*g2l[1] + b2l[1], 0.f);
        float z2 = fmaxf((h2[mt][2]-mean2)*rstd2*g2l[2] + b2l[2], 0.f);
        float z3 = fmaxf((h2[mt][3]-mean2)*rstd2*g2l[3] + b2l[3], 0.f);
        if (hasw) {
            z0 += bf2f(gv[mt].x); z1 += bf2f(gv[mt].y);
            z2 += bf2f(gv[mt].z); z3 += bf2f(gv[mt].w);
        }
        float4 o; o.x = z0; o.y = z1; o.z = z2; o.w = z3;
        *(float4*)(out + (size_t)row * 128 + col) = o;
    }
}

extern "C" void kernel_launch(void* const* d_in, const int* in_sizes, int n_in,
                              void* d_out, int out_size, void* d_ws, size_t ws_size,
                              hipStream_t stream)
{
    const float* fcoarse = (const float*)d_in[0];
    const float* ffine   = (const float*)d_in[1];
    const float* w1c = (const float*)d_in[2];
    const float* g1c = (const float*)d_in[3];
    const float* b1c = (const float*)d_in[4];
    const float* w2c = (const float*)d_in[5];
    const float* g2c = (const float*)d_in[6];
    const float* b2c = (const float*)d_in[7];
    const float* w1f = (const float*)d_in[8];
    const float* g1f = (const float*)d_in[9];
    const float* b1f = (const float*)d_in[10];
    const float* w2f = (const float*)d_in[11];
    const float* g2f = (const float*)d_in[12];
    const float* b2f = (const float*)d_in[13];
    const int* nrow  = (const int*)d_in[14];
    const int* ncol  = (const int*)d_in[15];

    float* out = (float*)d_out;
    const int Mc = 32768, Mf = 131072;

    // ws: fcB 8MB | winner 512KB | packs 160KB | folds 2KB | H1 33.5MB | stats 1MB
    unsigned short* fcB = (unsigned short*)d_ws;
    char* base = (char*)d_ws;
    int*   winner = (int*)(base + 8u*1024*1024);
    short* p1c = (short*)(base + 8u*1024*1024 + 512u*1024);
    short* p2c = p1c + 256*128;
    short* p1f = p2c + 128*128;
    short* p2f = p1f + 128*128;
    float* s2c = (float*)(p2f + 128*128);
    float* bwc = s2c + 128;
    float* s2f = bwc + 128;
    float* bwf = s2f + 128;
    unsigned short* H1ws = (unsigned short*)(base + 9078784u);
    float2* stats = (float2*)(base + 9078784u + 33554432u);
    const size_t WS_NEED_SPLIT = 9078784u + 33554432u + 1048576u;

    hipMemsetAsync(winner, 0xFF, (size_t)Mf * sizeof(int), stream);
    prep_kernel<<<42, 256, 0, stream>>>(w1c, w2c, g1c, b1c, w1f, w2f, g1f, b1f,
                                        p1c, p2c, p1f, p2f, s2c, bwc, s2f, bwf);

    // coarse MLP (512 blocks) + winner resolution (1024 blocks), one dispatch
    mlp_mfma<256, false><<<1024 + Mc/64, 256, 0, stream>>>(
        fcoarse, p1c, p2c, s2c, bwc, g2c, b2c,
        nullptr, fcB, nullptr, nullptr,
        nrow, ncol, winner, 1024);

    if (ws_size >= WS_NEED_SPLIT) {
        // ablation split: two separately-profiled fine phases
        fine_l1<<<Mf/64, 256, 0, stream>>>(ffine, p1f, H1ws, stats);
        fine_l2<<<Mf/64, 256, 0, stream>>>(H1ws, stats, p2f, s2f, bwf, g2f, b2f,
                                           winner, fcB, out);
    } else {
        // fallback: monolithic fine (R8)
        mlp_mfma<128, true><<<Mf/64, 256, 0, stream>>>(
            ffine, p1f, p2f, s2f, bwf, g2f, b2f,
            out, nullptr, winner, fcB,
            nullptr, nullptr, nullptr, 0);
    }
}

// Round 10
// 90.613 us; speedup vs baseline: 1.1978x; 1.1978x over previous
//
#include <hip/hip_runtime.h>
#include <hip/hip_bf16.h>

typedef __attribute__((ext_vector_type(8))) short s8v;            // 8 x bf16
typedef __attribute__((ext_vector_type(4))) float f4v;            // 4 x f32

__device__ __forceinline__ short f2bf(float f) {
    __hip_bfloat16 h = __float2bfloat16(f);
    union { __hip_bfloat16 h; short s; } u{h};
    return u.s;
}
__device__ __forceinline__ float bf2f(unsigned short v) {
    union { unsigned u; float f; } x; x.u = ((unsigned)v) << 16; return x.f;
}
__device__ __forceinline__ unsigned packbf(float a, float b) {
    return (unsigned)(unsigned short)f2bf(a) | ((unsigned)(unsigned short)f2bf(b) << 16);
}

// ---------------------------------------------------------------------------
// prep: blocks [0,40) pack weights (W2' = g1 o W2) into MFMA fragment order;
// blocks 40/41 compute LN1-folding vectors s2 = colsum(bf16(W2')), bW2 = b1@W2;
// blocks [42,170) zero the winner array (replaces the 40us hipMemsetAsync!).
// ---------------------------------------------------------------------------
__global__ void prep_kernel(const float* __restrict__ w1c, const float* __restrict__ w2c,
                            const float* __restrict__ g1c, const float* __restrict__ b1c,
                            const float* __restrict__ w1f, const float* __restrict__ w2f,
                            const float* __restrict__ g1f, const float* __restrict__ b1f,
                            short* __restrict__ p1c, short* __restrict__ p2c,
                            short* __restrict__ p1f, short* __restrict__ p2f,
                            float* __restrict__ s2c, float* __restrict__ bwc,
                            float* __restrict__ s2f, float* __restrict__ bwf,
                            int* __restrict__ win)
{
    int b = blockIdx.x, t = threadIdx.x;
    if (b >= 42) {                        // zero winner: 128 blocks x 256 thr x int4
        int idx4 = (b - 42) * 256 + t;
        int4 z; z.x = 0; z.y = 0; z.z = 0; z.w = 0;
        *(int4*)(win + idx4 * 4) = z;
        return;
    }
    if (b >= 40) {                        // folding vectors
        if (t >= 128) return;
        const float* W  = (b == 40) ? w2c : w2f;
        const float* g1 = (b == 40) ? g1c : g1f;
        const float* b1 = (b == 40) ? b1c : b1f;
        float* s2 = (b == 40) ? s2c : s2f;
        float* bw = (b == 40) ? bwc : bwf;
        float s = 0.f, w2sum = 0.f;
        for (int k = 0; k < 128; ++k) {
            float wv = W[k * 128 + t];
            s     += bf2f((unsigned short)f2bf(g1[k] * wv));  // match MFMA rounding
            w2sum += b1[k] * wv;
        }
        s2[t] = s; bw[t] = w2sum;
        return;
    }
    int id = b * 256 + t;                 // 40*256 = 160 frags * 64 lanes
    int f  = id >> 6, l = id & 63;
    const float* W; const float* g1 = nullptr; short* P; int fl;
    if      (f < 64)  { W = w1c; P = p1c; fl = f; }                   // K=256
    else if (f < 96)  { W = w2c; P = p2c; fl = f - 64;  g1 = g1c; }   // scaled
    else if (f < 128) { W = w1f; P = p1f; fl = f - 96; }
    else              { W = w2f; P = p2f; fl = f - 128; g1 = g1f; }   // scaled
    int g = l >> 4, c = l & 15;
    int ks = fl >> 3, n = fl & 7;
    s8v o;
    #pragma unroll
    for (int e = 0; e < 8; ++e) {
        int k = ks*32 + g*8 + e;
        float v = W[k * 128 + n*16 + c];
        if (g1) v *= g1[k];
        o[e] = f2bf(v);
    }
    *(s8v*)(P + ((fl*64 + l) << 3)) = o;
}

// ---------------------------------------------------------------------------
// Swapped-orientation fused MLP (lane owns one output row; LN lane-local + 2
// shuffles; LN1 folded into W2'), with per-wave LDS bounce so ALL bulk global
// I/O is coalesced (the R2-R9 limiter was per-lane-row scattered VMEM):
//   - X staged f32->bf16, consecutive lanes -> consecutive 16B (XOR-swizzled)
//   - epilogue values bounced through LDS, read back row-major so out stores
//     AND the fcB winner-gather are contiguous 256/512B per half-wave.
// winner[] encodes i+1 (0 = no winner) so prep can zero it cheaply.
// First nWinBlocks blocks do the winner atomicMax resolution instead.
// ---------------------------------------------------------------------------
template<int K1, bool FINE>
__global__ __launch_bounds__(256, 4)
void mlp_mfma(const float* __restrict__ X,
              const short* __restrict__ WpA,     // packed W1
              const short* __restrict__ WpB,     // packed W2' (g1-scaled)
              const float* __restrict__ s2v, const float* __restrict__ bwv,
              const float* __restrict__ g2v, const float* __restrict__ b2v,
              float* __restrict__ outF,            // FINE: f32 output
              unsigned short* __restrict__ outB,   // !FINE: bf16 fc output
              const int* __restrict__ winner,
              const unsigned short* __restrict__ fcB,
              const int* __restrict__ nr, const int* __restrict__ nc,
              int* __restrict__ win, int nWinBlocks)
{
    __shared__ __align__(16) unsigned char sbuf[4][8192];   // 8KB per wave

    if (blockIdx.x < (unsigned)nWinBlocks) {
        int i = blockIdx.x * 256 + threadIdx.x;
        atomicMax(&win[nr[i] * 32 + nc[i]], i + 1);
        return;
    }
    const int bid  = blockIdx.x - nWinBlocks;
    const int t    = threadIdx.x;
    const int wave = t >> 6, lane = t & 63;
    const int G = lane >> 4, n16 = lane & 15;
    const int wrow0 = bid * 64 + wave * 16;     // this wave's 16 rows
    char* sb = (char*)&sbuf[wave][0];

    int wv = 0;
    if constexpr (FINE) wv = winner[wrow0 + n16];

    // ---- Phase A: stage X rows to LDS, f32 -> bf16, coalesced + swizzled ----
    constexpr int NCH  = K1 / 4;     // float4 chunks per row (32 or 64)
    constexpr int ROWB = K1 * 2;     // bf16 row bytes (256 or 512)
    #pragma unroll
    for (int it = 0; it < NCH/4; ++it) {
        int i   = it*64 + lane;
        int row = i / NCH;
        int c4  = i % NCH;
        float4 v = *(const float4*)(X + (size_t)(wrow0 + row) * K1 + c4*4);
        uint2 p; p.x = packbf(v.x, v.y); p.y = packbf(v.z, v.w);
        int pg = (c4 >> 1) ^ row;                      // 16B-granule XOR swizzle
        *(uint2*)(sb + row*ROWB + pg*16 + (c4 & 1)*8) = p;
    }
    // per-wave LDS: no barrier needed (lgkmcnt ordering within the wave)

    // ---- Layer 1: acc1 = W1^T @ X^T ----
    f4v acc1[8];
    #pragma unroll
    for (int mt = 0; mt < 8; ++mt) acc1[mt] = (f4v){0.f, 0.f, 0.f, 0.f};

    const short* wpa = WpA + (lane << 3);
    #pragma unroll
    for (int kb = 0; kb < K1/128; ++kb) {
        s8v xf[4];
        #pragma unroll
        for (int k2 = 0; k2 < 4; ++k2) {
            int ks = kb*4 + k2;
            int pg = (ks*4 + G) ^ n16;
            xf[k2] = *(const s8v*)(sb + n16*ROWB + pg*16);
        }
        #pragma unroll
        for (int k2 = 0; k2 < 4; ++k2) {
            int ks = kb*4 + k2;
            s8v wfr[8];
            #pragma unroll
            for (int mt = 0; mt < 8; ++mt)
                wfr[mt] = *(const s8v*)(wpa + ((ks*8 + mt) << 9));
            #pragma unroll
            for (int mt = 0; mt < 8; ++mt)
                acc1[mt] = __builtin_amdgcn_mfma_f32_16x16x32_bf16(wfr[mt], xf[k2], acc1[mt], 0, 0, 0);
        }
    }

    // ---- LN1 stats (lane-local + 2 shuffle rounds) ----
    float sm = 0.f, sq = 0.f;
    #pragma unroll
    for (int mt = 0; mt < 8; ++mt)
        #pragma unroll
        for (int j = 0; j < 4; ++j) { float v = acc1[mt][j]; sm += v; sq += v*v; }
    sm += __shfl_xor(sm, 16, 64); sm += __shfl_xor(sm, 32, 64);
    sq += __shfl_xor(sq, 16, 64); sq += __shfl_xor(sq, 32, 64);
    const float mean1 = sm * (1.f/128.f);
    const float rstd1 = rsqrtf(sq * (1.f/128.f) - mean1*mean1 + 1e-5f);

    unsigned pk[8][2];
    #pragma unroll
    for (int mt = 0; mt < 8; ++mt) {
        pk[mt][0] = packbf(acc1[mt][0], acc1[mt][1]);
        pk[mt][1] = packbf(acc1[mt][2], acc1[mt][3]);
    }

    // ---- Layer 2: acc2 = W2'^T @ H1raw^T (B-frags built by shuffles) ----
    f4v acc2[8];
    #pragma unroll
    for (int mt = 0; mt < 8; ++mt) acc2[mt] = (f4v){0.f, 0.f, 0.f, 0.f};

    const short* wpb = WpB + (lane << 3);
    const int src0 = ((G & 1) << 5) + n16;
    const int src1 = src0 + 16;
    const bool hiG = (G >= 2);
    #pragma unroll
    for (int ks = 0; ks < 4; ++ks) {
        int r00 = __shfl((int)pk[2*ks][0],   src0, 64);
        int r01 = __shfl((int)pk[2*ks][1],   src0, 64);
        int r02 = __shfl((int)pk[2*ks][0],   src1, 64);
        int r03 = __shfl((int)pk[2*ks][1],   src1, 64);
        int r10 = __shfl((int)pk[2*ks+1][0], src0, 64);
        int r11 = __shfl((int)pk[2*ks+1][1], src0, 64);
        int r12 = __shfl((int)pk[2*ks+1][0], src1, 64);
        int r13 = __shfl((int)pk[2*ks+1][1], src1, 64);
        union { int u[4]; s8v v; } hb;
        hb.u[0] = hiG ? r10 : r00; hb.u[1] = hiG ? r11 : r01;
        hb.u[2] = hiG ? r12 : r02; hb.u[3] = hiG ? r13 : r03;
        s8v wfr[8];
        #pragma unroll
        for (int mt = 0; mt < 8; ++mt)
            wfr[mt] = *(const s8v*)(wpb + ((ks*8 + mt) << 9));
        #pragma unroll
        for (int mt = 0; mt < 8; ++mt)
            acc2[mt] = __builtin_amdgcn_mfma_f32_16x16x32_bf16(wfr[mt], hb.v, acc2[mt], 0, 0, 0);
    }

    // ---- folded LN1 apply + LN2 stats ----
    float h2[8][4];
    float sm2 = 0.f, sq2 = 0.f;
    #pragma unroll
    for (int mt = 0; mt < 8; ++mt) {
        const int col = mt*16 + G*4;
        f4v s2l = *(const f4v*)&s2v[col];
        f4v bwl = *(const f4v*)&bwv[col];
        #pragma unroll
        for (int j = 0; j < 4; ++j) {
            float v = rstd1 * (acc2[mt][j] - mean1 * s2l[j]) + bwl[j];
            h2[mt][j] = v; sm2 += v; sq2 += v*v;
        }
    }
    sm2 += __shfl_xor(sm2, 16, 64); sm2 += __shfl_xor(sm2, 32, 64);
    sq2 += __shfl_xor(sq2, 16, 64); sq2 += __shfl_xor(sq2, 32, 64);
    const float mean2 = sm2 * (1.f/128.f);
    const float rstd2 = rsqrtf(sq2 * (1.f/128.f) - mean2*mean2 + 1e-5f);

    // ---- epilogue: LN2+ReLU -> LDS bounce -> coalesced (+gather) store ----
    if constexpr (FINE) {
        #pragma unroll
        for (int mt = 0; mt < 8; ++mt) {
            const int col = mt*16 + G*4;
            f4v g2l = *(const f4v*)&g2v[col];
            f4v b2l = *(const f4v*)&b2v[col];
            float4 z;
            z.x = fmaxf((h2[mt][0]-mean2)*rstd2*g2l[0] + b2l[0], 0.f);
            z.y = fmaxf((h2[mt][1]-mean2)*rstd2*g2l[1] + b2l[1], 0.f);
            z.z = fmaxf((h2[mt][2]-mean2)*rstd2*g2l[2] + b2l[2], 0.f);
            z.w = fmaxf((h2[mt][3]-mean2)*rstd2*g2l[3] + b2l[3], 0.f);
            int pg = (mt*4 + G) ^ n16;           // 32 granules/row, XOR swizzle
            *(float4*)(sb + n16*512 + pg*16) = z;
        }
        #pragma unroll
        for (int it = 0; it < 8; ++it) {
            int row = it*2 + (lane >> 5);
            int g32 = lane & 31;
            float4 zv = *(const float4*)(sb + row*512 + ((g32 ^ row)*16));
            int w = __shfl(wv, row, 64);
            if (w > 0) {
                const ushort4 u = *(const ushort4*)(fcB + (size_t)((w-1) & 32767) * 128 + g32*4);
                zv.x += bf2f(u.x); zv.y += bf2f(u.y);
                zv.z += bf2f(u.z); zv.w += bf2f(u.w);
            }
            *(float4*)(outF + (size_t)(wrow0 + row) * 128 + g32*4) = zv;
        }
    } else {
        #pragma unroll
        for (int mt = 0; mt < 8; ++mt) {
            const int col = mt*16 + G*4;
            f4v g2l = *(const f4v*)&g2v[col];
            f4v b2l = *(const f4v*)&b2v[col];
            uint2 p;
            p.x = packbf(fmaxf((h2[mt][0]-mean2)*rstd2*g2l[0] + b2l[0], 0.f),
                         fmaxf((h2[mt][1]-mean2)*rstd2*g2l[1] + b2l[1], 0.f));
            p.y = packbf(fmaxf((h2[mt][2]-mean2)*rstd2*g2l[2] + b2l[2], 0.f),
                         fmaxf((h2[mt][3]-mean2)*rstd2*g2l[3] + b2l[3], 0.f));
            int pg = (mt*2 + (G >> 1)) ^ n16;    // 16 granules/row
            *(uint2*)(sb + n16*256 + pg*16 + (G & 1)*8) = p;
        }
        #pragma unroll
        for (int it = 0; it < 4; ++it) {
            int row = it*4 + (lane >> 4);
            int g16 = lane & 15;
            s8v v = *(const s8v*)(sb + row*256 + ((g16 ^ row)*16));
            *(s8v*)(outB + (size_t)(wrow0 + row) * 128 + g16*8) = v;
        }
    }
}

extern "C" void kernel_launch(void* const* d_in, const int* in_sizes, int n_in,
                              void* d_out, int out_size, void* d_ws, size_t ws_size,
                              hipStream_t stream)
{
    const float* fcoarse = (const float*)d_in[0];
    const float* ffine   = (const float*)d_in[1];
    const float* w1c = (const float*)d_in[2];
    const float* g1c = (const float*)d_in[3];
    const float* b1c = (const float*)d_in[4];
    const float* w2c = (const float*)d_in[5];
    const float* g2c = (const float*)d_in[6];
    const float* b2c = (const float*)d_in[7];
    const float* w1f = (const float*)d_in[8];
    const float* g1f = (const float*)d_in[9];
    const float* b1f = (const float*)d_in[10];
    const float* w2f = (const float*)d_in[11];
    const float* g2f = (const float*)d_in[12];
    const float* b2f = (const float*)d_in[13];
    const int* nrow  = (const int*)d_in[14];
    const int* ncol  = (const int*)d_in[15];

    float* out = (float*)d_out;
    const int Mc = 32768, Mf = 131072;

    // ws: fcB 8MB | winner 512KB | packs 160KB | fold vecs 2KB
    unsigned short* fcB = (unsigned short*)d_ws;
    char* base = (char*)d_ws;
    int*   winner = (int*)(base + 8u*1024*1024);
    short* p1c = (short*)(base + 8u*1024*1024 + 512u*1024);
    short* p2c = p1c + 256*128;
    short* p1f = p2c + 128*128;
    short* p2f = p1f + 128*128;
    float* s2c = (float*)(p2f + 128*128);
    float* bwc = s2c + 128;
    float* s2f = bwc + 128;
    float* bwf = s2f + 128;

    // prep: pack weights + fold vectors + zero winner (no hipMemsetAsync!)
    prep_kernel<<<170, 256, 0, stream>>>(w1c, w2c, g1c, b1c, w1f, w2f, g1f, b1f,
                                         p1c, p2c, p1f, p2f, s2c, bwc, s2f, bwf,
                                         winner);

    // coarse MLP (512 blocks) + winner resolution (1024 blocks), one dispatch
    mlp_mfma<256, false><<<1024 + Mc/64, 256, 0, stream>>>(
        fcoarse, p1c, p2c, s2c, bwc, g2c, b2c,
        nullptr, fcB, nullptr, nullptr,
        nrow, ncol, winner, 1024);

    // fine MLP + fused scatter -> out
    mlp_mfma<128, true><<<Mf/64, 256, 0, stream>>>(
        ffine, p1f, p2f, s2f, bwf, g2f, b2f,
        out, nullptr, winner, fcB,
        nullptr, nullptr, nullptr, 0);
}

// Round 11
// 79.319 us; speedup vs baseline: 1.3683x; 1.1424x over previous
//
#include <hip/hip_runtime.h>
#include <hip/hip_bf16.h>

typedef __attribute__((ext_vector_type(8))) short s8v;            // 8 x bf16
typedef __attribute__((ext_vector_type(4))) float f4v;            // 4 x f32

__device__ __forceinline__ short f2bf(float f) {
    __hip_bfloat16 h = __float2bfloat16(f);
    union { __hip_bfloat16 h; short s; } u{h};
    return u.s;
}
__device__ __forceinline__ float bf2f(unsigned short v) {
    union { unsigned u; float f; } x; x.u = ((unsigned)v) << 16; return x.f;
}
__device__ __forceinline__ unsigned packbf(float a, float b) {
    return (unsigned)(unsigned short)f2bf(a) | ((unsigned)(unsigned short)f2bf(b) << 16);
}

// ---------------------------------------------------------------------------
// prep: blocks [0,40) pack weights (W2' = g1 o W2) into MFMA fragment order;
// blocks 40/41 compute LN1-folding vectors s2 = colsum(bf16(W2')), bW2 = b1@W2;
// blocks [42,170) zero the winner array (no hipMemsetAsync - it cost 40us).
// ---------------------------------------------------------------------------
__global__ void prep_kernel(const float* __restrict__ w1c, const float* __restrict__ w2c,
                            const float* __restrict__ g1c, const float* __restrict__ b1c,
                            const float* __restrict__ w1f, const float* __restrict__ w2f,
                            const float* __restrict__ g1f, const float* __restrict__ b1f,
                            short* __restrict__ p1c, short* __restrict__ p2c,
                            short* __restrict__ p1f, short* __restrict__ p2f,
                            float* __restrict__ s2c, float* __restrict__ bwc,
                            float* __restrict__ s2f, float* __restrict__ bwf,
                            int* __restrict__ win)
{
    int b = blockIdx.x, t = threadIdx.x;
    if (b >= 42) {                        // zero winner: 128 blocks x 256 thr x int4
        int idx4 = (b - 42) * 256 + t;
        int4 z; z.x = 0; z.y = 0; z.z = 0; z.w = 0;
        *(int4*)(win + idx4 * 4) = z;
        return;
    }
    if (b >= 40) {                        // folding vectors
        if (t >= 128) return;
        const float* W  = (b == 40) ? w2c : w2f;
        const float* g1 = (b == 40) ? g1c : g1f;
        const float* b1 = (b == 40) ? b1c : b1f;
        float* s2 = (b == 40) ? s2c : s2f;
        float* bw = (b == 40) ? bwc : bwf;
        float s = 0.f, w2sum = 0.f;
        for (int k = 0; k < 128; ++k) {
            float wv = W[k * 128 + t];
            s     += bf2f((unsigned short)f2bf(g1[k] * wv));  // match MFMA rounding
            w2sum += b1[k] * wv;
        }
        s2[t] = s; bw[t] = w2sum;
        return;
    }
    int id = b * 256 + t;                 // 40*256 = 160 frags * 64 lanes
    int f  = id >> 6, l = id & 63;
    const float* W; const float* g1 = nullptr; short* P; int fl;
    if      (f < 64)  { W = w1c; P = p1c; fl = f; }                   // K=256
    else if (f < 96)  { W = w2c; P = p2c; fl = f - 64;  g1 = g1c; }   // scaled
    else if (f < 128) { W = w1f; P = p1f; fl = f - 96; }
    else              { W = w2f; P = p2f; fl = f - 128; g1 = g1f; }   // scaled
    int g = l >> 4, c = l & 15;
    int ks = fl >> 3, n = fl & 7;
    s8v o;
    #pragma unroll
    for (int e = 0; e < 8; ++e) {
        int k = ks*32 + g*8 + e;
        float v = W[k * 128 + n*16 + c];
        if (g1) v *= g1[k];
        o[e] = f2bf(v);
    }
    *(s8v*)(P + ((fl*64 + l) << 3)) = o;
}

// ---------------------------------------------------------------------------
// Swapped-orientation fused MLP (lane owns one output row; lane-local LN +
// 2 shuffle rounds; LN1 folded into W2') with BLOCK-LDS-RESIDENT WEIGHTS:
// 1024 threads = 16 waves share one 64KB staged copy of the packed weights,
// replacing the ~64 per-wave L2 fragment loads (the R2-R10 latency pole)
// with conflict-free ds_read_b128.
//   fine  (K1=128): W1(32KB)@Ws[0] + W2'(32KB)@Ws[16384], staged once.
//   coarse(K1=256): W1(64KB)@Ws[0]; after L1 re-stage W2'(32KB)@Ws[0].
// First nWinBlocks blocks do winner atomicMax resolution instead (i+1 enc).
// ---------------------------------------------------------------------------
template<int K1, bool FINE>
__global__ __launch_bounds__(1024, 4)
void mlp_mfma(const float* __restrict__ X,
              const short* __restrict__ WpA,     // packed W1
              const short* __restrict__ WpB,     // packed W2' (g1-scaled)
              const float* __restrict__ s2v, const float* __restrict__ bwv,
              const float* __restrict__ g2v, const float* __restrict__ b2v,
              float* __restrict__ outF,            // FINE: f32 output
              unsigned short* __restrict__ outB,   // !FINE: bf16 fc output
              const int* __restrict__ winner,
              const unsigned short* __restrict__ fcB,
              const int* __restrict__ nr, const int* __restrict__ nc,
              int* __restrict__ win, int nWinBlocks)
{
    constexpr int NF1 = (K1/32) * 8;           // 32 (fine) or 64 (coarse) frags
    __shared__ short Ws[32768];                // 64 KB
    constexpr int W2OFF = (K1 == 128) ? 16384 : 0;

    if (blockIdx.x < (unsigned)nWinBlocks) {
        int i = blockIdx.x * 1024 + threadIdx.x;
        atomicMax(&win[nr[i] * 32 + nc[i]], i + 1);
        return;
    }
    const int bid  = blockIdx.x - nWinBlocks;
    const int tid  = threadIdx.x;
    const int wave = tid >> 6, lane = tid & 63;
    const int G = lane >> 4, n16 = lane & 15;
    const int row = bid * 256 + wave * 16 + n16;     // this lane's x_row
    const size_t rowK = (size_t)row * K1;

    // ---- stage W1 (and W2 for fine) into LDS, coalesced 16B chunks ----
    #pragma unroll
    for (int r = 0; r < NF1/16; ++r) {               // fine 2, coarse 4 rounds
        int ch = r*1024 + tid;
        *(s8v*)&Ws[ch*8] = *(const s8v*)(WpA + (size_t)ch*8);
    }
    if constexpr (K1 == 128) {
        #pragma unroll
        for (int r = 0; r < 2; ++r) {
            int ch = r*1024 + tid;
            *(s8v*)&Ws[16384 + ch*8] = *(const s8v*)(WpB + (size_t)ch*8);
        }
    }
    __syncthreads();

    int wv = 0;
    if constexpr (FINE) wv = winner[row];

    // ---------------- Layer 1: acc1 = W1^T @ X^T ----------------
    f4v acc1[8];
    #pragma unroll
    for (int mt = 0; mt < 8; ++mt) acc1[mt] = (f4v){0.f, 0.f, 0.f, 0.f};

    const float* pX = X + rowK + G*8;
    #pragma unroll
    for (int kb = 0; kb < K1/32; kb += 4) {
        float4 aPf[4][2];
        #pragma unroll
        for (int k2 = 0; k2 < 4; ++k2) {
            aPf[k2][0] = *(const float4*)(pX + (kb + k2)*32);
            aPf[k2][1] = *(const float4*)(pX + (kb + k2)*32 + 4);
        }
        #pragma unroll
        for (int k2 = 0; k2 < 4; ++k2) {
            const int ks = kb + k2;
            s8v wfr[8];
            #pragma unroll
            for (int mt = 0; mt < 8; ++mt)
                wfr[mt] = *(const s8v*)&Ws[((ks*8 + mt)*64 + lane) * 8];
            s8v xf;
            xf[0] = f2bf(aPf[k2][0].x); xf[1] = f2bf(aPf[k2][0].y);
            xf[2] = f2bf(aPf[k2][0].z); xf[3] = f2bf(aPf[k2][0].w);
            xf[4] = f2bf(aPf[k2][1].x); xf[5] = f2bf(aPf[k2][1].y);
            xf[6] = f2bf(aPf[k2][1].z); xf[7] = f2bf(aPf[k2][1].w);
            #pragma unroll
            for (int mt = 0; mt < 8; ++mt)
                acc1[mt] = __builtin_amdgcn_mfma_f32_16x16x32_bf16(wfr[mt], xf, acc1[mt], 0, 0, 0);
        }
    }

    // coarse: re-stage W2' over W1 (all waves finished reading W1)
    if constexpr (K1 == 256) {
        __syncthreads();
        #pragma unroll
        for (int r = 0; r < 2; ++r) {
            int ch = r*1024 + tid;
            *(s8v*)&Ws[ch*8] = *(const s8v*)(WpB + (size_t)ch*8);
        }
        __syncthreads();
    }

    // ---------------- LN1 stats (lane-local + 2 shuffle rounds) ----------------
    float sm = 0.f, sq = 0.f;
    #pragma unroll
    for (int mt = 0; mt < 8; ++mt)
        #pragma unroll
        for (int j = 0; j < 4; ++j) { float v = acc1[mt][j]; sm += v; sq += v*v; }
    sm += __shfl_xor(sm, 16, 64); sm += __shfl_xor(sm, 32, 64);
    sq += __shfl_xor(sq, 16, 64); sq += __shfl_xor(sq, 32, 64);
    const float mean1 = sm * (1.f/128.f);
    const float rstd1 = rsqrtf(sq * (1.f/128.f) - mean1*mean1 + 1e-5f);

    unsigned pk[8][2];
    #pragma unroll
    for (int mt = 0; mt < 8; ++mt) {
        pk[mt][0] = packbf(acc1[mt][0], acc1[mt][1]);
        pk[mt][1] = packbf(acc1[mt][2], acc1[mt][3]);
    }

    // ---------------- Layer 2: acc2 = W2'^T @ H1raw^T ----------------
    f4v acc2[8];
    #pragma unroll
    for (int mt = 0; mt < 8; ++mt) acc2[mt] = (f4v){0.f, 0.f, 0.f, 0.f};

    const int src0 = ((G & 1) << 5) + n16;
    const int src1 = src0 + 16;
    const bool hiG = (G >= 2);
    #pragma unroll
    for (int ks = 0; ks < 4; ++ks) {
        int r00 = __shfl((int)pk[2*ks][0],   src0, 64);
        int r01 = __shfl((int)pk[2*ks][1],   src0, 64);
        int r02 = __shfl((int)pk[2*ks][0],   src1, 64);
        int r03 = __shfl((int)pk[2*ks][1],   src1, 64);
        int r10 = __shfl((int)pk[2*ks+1][0], src0, 64);
        int r11 = __shfl((int)pk[2*ks+1][1], src0, 64);
        int r12 = __shfl((int)pk[2*ks+1][0], src1, 64);
        int r13 = __shfl((int)pk[2*ks+1][1], src1, 64);
        union { int u[4]; s8v v; } hb;
        hb.u[0] = hiG ? r10 : r00; hb.u[1] = hiG ? r11 : r01;
        hb.u[2] = hiG ? r12 : r02; hb.u[3] = hiG ? r13 : r03;
        s8v wfr[8];
        #pragma unroll
        for (int mt = 0; mt < 8; ++mt)
            wfr[mt] = *(const s8v*)&Ws[W2OFF + ((ks*8 + mt)*64 + lane) * 8];
        #pragma unroll
        for (int mt = 0; mt < 8; ++mt)
            acc2[mt] = __builtin_amdgcn_mfma_f32_16x16x32_bf16(wfr[mt], hb.v, acc2[mt], 0, 0, 0);
    }

    // ---------------- folded LN1 apply + LN2 stats ----------------
    float h2[8][4];
    float sm2 = 0.f, sq2 = 0.f;
    #pragma unroll
    for (int mt = 0; mt < 8; ++mt) {
        const int col = mt*16 + G*4;
        f4v s2l = *(const f4v*)&s2v[col];
        f4v bwl = *(const f4v*)&bwv[col];
        #pragma unroll
        for (int j = 0; j < 4; ++j) {
            float v = rstd1 * (acc2[mt][j] - mean1 * s2l[j]) + bwl[j];
            h2[mt][j] = v; sm2 += v; sq2 += v*v;
        }
    }
    sm2 += __shfl_xor(sm2, 16, 64); sm2 += __shfl_xor(sm2, 32, 64);
    sq2 += __shfl_xor(sq2, 16, 64); sq2 += __shfl_xor(sq2, 32, 64);
    const float mean2 = sm2 * (1.f/128.f);
    const float rstd2 = rsqrtf(sq2 * (1.f/128.f) - mean2*mean2 + 1e-5f);

    // ---------------- LN2 + ReLU + (FINE: gather-add) + store ----------------
    if constexpr (FINE) {
        ushort4 gv[8];
        const bool hasw = (wv > 0);
        const size_t src = (size_t)((wv - 1) & 32767) * 128;
        if (hasw) {
            #pragma unroll
            for (int mt = 0; mt < 8; ++mt)
                gv[mt] = *(const ushort4*)(fcB + src + mt*16 + G*4);
        }
        #pragma unroll
        for (int mt = 0; mt < 8; ++mt) {
            const int col = mt*16 + G*4;
            f4v g2l = *(const f4v*)&g2v[col];
            f4v b2l = *(const f4v*)&b2v[col];
            float z0 = fmaxf((h2[mt][0]-mean2)*rstd2*g2l[0] + b2l[0], 0.f);
            float z1 = fmaxf((h2[mt][1]-mean2)*rstd2*g2l[1] + b2l[1], 0.f);
            float z2 = fmaxf((h2[mt][2]-mean2)*rstd2*g2l[2] + b2l[2], 0.f);
            float z3 = fmaxf((h2[mt][3]-mean2)*rstd2*g2l[3] + b2l[3], 0.f);
            if (hasw) {
                z0 += bf2f(gv[mt].x); z1 += bf2f(gv[mt].y);
                z2 += bf2f(gv[mt].z); z3 += bf2f(gv[mt].w);
            }
            float4 o; o.x = z0; o.y = z1; o.z = z2; o.w = z3;
            *(float4*)(outF + (size_t)row * 128 + col) = o;
        }
    } else {
        #pragma unroll
        for (int mt = 0; mt < 8; ++mt) {
            const int col = mt*16 + G*4;
            f4v g2l = *(const f4v*)&g2v[col];
            f4v b2l = *(const f4v*)&b2v[col];
            ushort4 o;
            o.x = (unsigned short)f2bf(fmaxf((h2[mt][0]-mean2)*rstd2*g2l[0] + b2l[0], 0.f));
            o.y = (unsigned short)f2bf(fmaxf((h2[mt][1]-mean2)*rstd2*g2l[1] + b2l[1], 0.f));
            o.z = (unsigned short)f2bf(fmaxf((h2[mt][2]-mean2)*rstd2*g2l[2] + b2l[2], 0.f));
            o.w = (unsigned short)f2bf(fmaxf((h2[mt][3]-mean2)*rstd2*g2l[3] + b2l[3], 0.f));
            *(ushort4*)(outB + (size_t)row * 128 + col) = o;
        }
    }
}

extern "C" void kernel_launch(void* const* d_in, const int* in_sizes, int n_in,
                              void* d_out, int out_size, void* d_ws, size_t ws_size,
                              hipStream_t stream)
{
    const float* fcoarse = (const float*)d_in[0];
    const float* ffine   = (const float*)d_in[1];
    const float* w1c = (const float*)d_in[2];
    const float* g1c = (const float*)d_in[3];
    const float* b1c = (const float*)d_in[4];
    const float* w2c = (const float*)d_in[5];
    const float* g2c = (const float*)d_in[6];
    const float* b2c = (const float*)d_in[7];
    const float* w1f = (const float*)d_in[8];
    const float* g1f = (const float*)d_in[9];
    const float* b1f = (const float*)d_in[10];
    const float* w2f = (const float*)d_in[11];
    const float* g2f = (const float*)d_in[12];
    const float* b2f = (const float*)d_in[13];
    const int* nrow  = (const int*)d_in[14];
    const int* ncol  = (const int*)d_in[15];

    float* out = (float*)d_out;
    const int Mc = 32768, Mf = 131072;

    // ws: fcB 8MB | winner 512KB | packs 160KB | fold vecs 2KB
    unsigned short* fcB = (unsigned short*)d_ws;
    char* base = (char*)d_ws;
    int*   winner = (int*)(base + 8u*1024*1024);
    short* p1c = (short*)(base + 8u*1024*1024 + 512u*1024);
    short* p2c = p1c + 256*128;
    short* p1f = p2c + 128*128;
    short* p2f = p1f + 128*128;
    float* s2c = (float*)(p2f + 128*128);
    float* bwc = s2c + 128;
    float* s2f = bwc + 128;
    float* bwf = s2f + 128;

    // prep: pack weights + fold vectors + zero winner
    prep_kernel<<<170, 256, 0, stream>>>(w1c, w2c, g1c, b1c, w1f, w2f, g1f, b1f,
                                         p1c, p2c, p1f, p2f, s2c, bwc, s2f, bwf,
                                         winner);

    // coarse MLP (128 blocks of 256 rows) + winner resolution (256 blocks)
    mlp_mfma<256, false><<<256 + Mc/256, 1024, 0, stream>>>(
        fcoarse, p1c, p2c, s2c, bwc, g2c, b2c,
        nullptr, fcB, nullptr, nullptr,
        nrow, ncol, winner, 256);

    // fine MLP + fused scatter -> out (512 blocks of 256 rows)
    mlp_mfma<128, true><<<Mf/256, 1024, 0, stream>>>(
        ffine, p1f, p2f, s2f, bwf, g2f, b2f,
        out, nullptr, winner, fcB,
        nullptr, nullptr, nullptr, 0);
}

// Round 12
// 74.352 us; speedup vs baseline: 1.4597x; 1.0668x over previous
//
#include <hip/hip_runtime.h>
#include <hip/hip_bf16.h>

typedef __attribute__((ext_vector_type(8))) short s8v;            // 8 x bf16
typedef __attribute__((ext_vector_type(4))) float f4v;            // 4 x f32

__device__ __forceinline__ short f2bf(float f) {
    __hip_bfloat16 h = __float2bfloat16(f);
    union { __hip_bfloat16 h; short s; } u{h};
    return u.s;
}
__device__ __forceinline__ float bf2f(unsigned short v) {
    union { unsigned u; float f; } x; x.u = ((unsigned)v) << 16; return x.f;
}
__device__ __forceinline__ unsigned packbf(float a, float b) {
    return (unsigned)(unsigned short)f2bf(a) | ((unsigned)(unsigned short)f2bf(b) << 16);
}

// ---------------------------------------------------------------------------
// prep: blocks [0,40) pack weights (W2' = g1 o W2) into MFMA fragment order;
// blocks 40/41 compute LN1-folding vectors s2 = colsum(bf16(W2')), bW2 = b1@W2;
// blocks [42,170) zero the winner array (hipMemsetAsync cost 40us - never again).
// ---------------------------------------------------------------------------
__global__ void prep_kernel(const float* __restrict__ w1c, const float* __restrict__ w2c,
                            const float* __restrict__ g1c, const float* __restrict__ b1c,
                            const float* __restrict__ w1f, const float* __restrict__ w2f,
                            const float* __restrict__ g1f, const float* __restrict__ b1f,
                            short* __restrict__ p1c, short* __restrict__ p2c,
                            short* __restrict__ p1f, short* __restrict__ p2f,
                            float* __restrict__ s2c, float* __restrict__ bwc,
                            float* __restrict__ s2f, float* __restrict__ bwf,
                            int* __restrict__ win)
{
    int b = blockIdx.x, t = threadIdx.x;
    if (b >= 42) {                        // zero winner: 128 blocks x 256 thr x int4
        int idx4 = (b - 42) * 256 + t;
        int4 z; z.x = 0; z.y = 0; z.z = 0; z.w = 0;
        *(int4*)(win + idx4 * 4) = z;
        return;
    }
    if (b >= 40) {                        // folding vectors
        if (t >= 128) return;
        const float* W  = (b == 40) ? w2c : w2f;
        const float* g1 = (b == 40) ? g1c : g1f;
        const float* b1 = (b == 40) ? b1c : b1f;
        float* s2 = (b == 40) ? s2c : s2f;
        float* bw = (b == 40) ? bwc : bwf;
        float s = 0.f, w2sum = 0.f;
        for (int k = 0; k < 128; ++k) {
            float wv = W[k * 128 + t];
            s     += bf2f((unsigned short)f2bf(g1[k] * wv));  // match MFMA rounding
            w2sum += b1[k] * wv;
        }
        s2[t] = s; bw[t] = w2sum;
        return;
    }
    int id = b * 256 + t;                 // 40*256 = 160 frags * 64 lanes
    int f  = id >> 6, l = id & 63;
    const float* W; const float* g1 = nullptr; short* P; int fl;
    if      (f < 64)  { W = w1c; P = p1c; fl = f; }                   // K=256
    else if (f < 96)  { W = w2c; P = p2c; fl = f - 64;  g1 = g1c; }   // scaled
    else if (f < 128) { W = w1f; P = p1f; fl = f - 96; }
    else              { W = w2f; P = p2f; fl = f - 128; g1 = g1f; }   // scaled
    int g = l >> 4, c = l & 15;
    int ks = fl >> 3, n = fl & 7;
    s8v o;
    #pragma unroll
    for (int e = 0; e < 8; ++e) {
        int k = ks*32 + g*8 + e;
        float v = W[k * 128 + n*16 + c];
        if (g1) v *= g1[k];
        o[e] = f2bf(v);
    }
    *(s8v*)(P + ((fl*64 + l) << 3)) = o;
}

// ---------------------------------------------------------------------------
// Swapped-orientation fused MLP (lane owns one output row; lane-local LN +
// 2 shuffle rounds; LN1 folded into W2'). Weights block-LDS-resident (R11 win).
// R12 change: 512-thread blocks -> 128-VGPR budget (vs 64 at 1024thr), and ALL
// per-wave global loads (winner -> X -> gather) are issued BEFORE the staging
// barrier so its vmcnt(0) drain collapses ~25 serialized latency exposures
// into one concurrent wall; post-barrier compute is stall-free.
//   fine  (K1=128): W1(32KB)@Ws[0] + W2'(32KB)@Ws[16384], staged once.
//   coarse(K1=256): W1(64KB)@Ws[0]; after L1, re-stage W2'(32KB)@Ws[0].
// First nWinBlocks blocks do winner atomicMax resolution instead (i+1 enc).
// ---------------------------------------------------------------------------
template<int K1, bool FINE>
__global__ __launch_bounds__(512, 4)
void mlp_mfma(const float* __restrict__ X,
              const short* __restrict__ WpA,     // packed W1
              const short* __restrict__ WpB,     // packed W2' (g1-scaled)
              const float* __restrict__ s2v, const float* __restrict__ bwv,
              const float* __restrict__ g2v, const float* __restrict__ b2v,
              float* __restrict__ outF,            // FINE: f32 output
              unsigned short* __restrict__ outB,   // !FINE: bf16 fc output
              const int* __restrict__ winner,
              const unsigned short* __restrict__ fcB,
              const int* __restrict__ nr, const int* __restrict__ nc,
              int* __restrict__ win, int nWinBlocks)
{
    __shared__ short Ws[32768];                // 64 KB
    constexpr int W2OFF = (K1 == 128) ? 16384 : 0;

    if (blockIdx.x < (unsigned)nWinBlocks) {
        int i = blockIdx.x * 512 + threadIdx.x;
        atomicMax(&win[nr[i] * 32 + nc[i]], i + 1);
        return;
    }
    const int bid  = blockIdx.x - nWinBlocks;
    const int tid  = threadIdx.x;
    const int wave = tid >> 6, lane = tid & 63;
    const int G = lane >> 4, n16 = lane & 15;
    const int row = bid * 128 + wave * 16 + n16;     // this lane's x_row
    const size_t rowK = (size_t)row * K1;

    // ---- (1) winner load first (gather depends on it) ----
    int wv = 0;
    if constexpr (FINE) wv = winner[row];

    // ---- (2) stage W1 (and W2' for fine) into LDS, coalesced 16B chunks ----
    #pragma unroll
    for (int r = 0; r < (K1 == 128 ? 4 : 8); ++r) {
        int ch = r*512 + tid;
        *(s8v*)&Ws[ch*8] = *(const s8v*)(WpA + (size_t)ch*8);
    }
    if constexpr (K1 == 128) {
        #pragma unroll
        for (int r = 0; r < 4; ++r) {
            int ch = r*512 + tid;
            *(s8v*)&Ws[16384 + ch*8] = *(const s8v*)(WpB + (size_t)ch*8);
        }
    }

    // ---- (3) prefetch X fragments (first 4 k-slices; all of fine's K) ----
    const float* pX = X + rowK + G*8;
    float4 aPf[4][2];
    #pragma unroll
    for (int k2 = 0; k2 < 4; ++k2) {
        aPf[k2][0] = *(const float4*)(pX + k2*32);
        aPf[k2][1] = *(const float4*)(pX + k2*32 + 4);
    }

    // ---- (4) prefetch ALL gather rows (winner known; fcB from prev dispatch) ----
    ushort4 gv[8];
    bool hasw = false;
    if constexpr (FINE) {
        hasw = (wv > 0);
        const size_t src = (size_t)((wv - 1) & 32767) * 128;
        if (hasw) {
            #pragma unroll
            for (int mt = 0; mt < 8; ++mt)
                gv[mt] = *(const ushort4*)(fcB + src + mt*16 + G*4);
        }
    }

    // ---- (5) barrier: drains ALL the above loads concurrently ----
    __syncthreads();

    // ---------------- Layer 1: acc1 = W1^T @ X^T ----------------
    f4v acc1[8];
    #pragma unroll
    for (int mt = 0; mt < 8; ++mt) acc1[mt] = (f4v){0.f, 0.f, 0.f, 0.f};

    #pragma unroll
    for (int kb = 0; kb < K1/32; kb += 4) {
        #pragma unroll
        for (int k2 = 0; k2 < 4; ++k2) {
            const int ks = kb + k2;
            s8v wfr[8];
            #pragma unroll
            for (int mt = 0; mt < 8; ++mt)
                wfr[mt] = *(const s8v*)&Ws[((ks*8 + mt)*64 + lane) * 8];
            s8v xf;
            xf[0] = f2bf(aPf[k2][0].x); xf[1] = f2bf(aPf[k2][0].y);
            xf[2] = f2bf(aPf[k2][0].z); xf[3] = f2bf(aPf[k2][0].w);
            xf[4] = f2bf(aPf[k2][1].x); xf[5] = f2bf(aPf[k2][1].y);
            xf[6] = f2bf(aPf[k2][1].z); xf[7] = f2bf(aPf[k2][1].w);
            #pragma unroll
            for (int mt = 0; mt < 8; ++mt)
                acc1[mt] = __builtin_amdgcn_mfma_f32_16x16x32_bf16(wfr[mt], xf, acc1[mt], 0, 0, 0);
        }
        if (kb + 4 < K1/32) {               // coarse: refill X for next 4 slices
            #pragma unroll
            for (int k2 = 0; k2 < 4; ++k2) {
                aPf[k2][0] = *(const float4*)(pX + (kb+4+k2)*32);
                aPf[k2][1] = *(const float4*)(pX + (kb+4+k2)*32 + 4);
            }
        }
    }

    // coarse: re-stage W2' over W1 (all waves done reading W1)
    if constexpr (K1 == 256) {
        __syncthreads();
        #pragma unroll
        for (int r = 0; r < 4; ++r) {
            int ch = r*512 + tid;
            *(s8v*)&Ws[ch*8] = *(const s8v*)(WpB + (size_t)ch*8);
        }
        __syncthreads();
    }

    // ---------------- LN1 stats (lane-local + 2 shuffle rounds) ----------------
    float sm = 0.f, sq = 0.f;
    #pragma unroll
    for (int mt = 0; mt < 8; ++mt)
        #pragma unroll
        for (int j = 0; j < 4; ++j) { float v = acc1[mt][j]; sm += v; sq += v*v; }
    sm += __shfl_xor(sm, 16, 64); sm += __shfl_xor(sm, 32, 64);
    sq += __shfl_xor(sq, 16, 64); sq += __shfl_xor(sq, 32, 64);
    const float mean1 = sm * (1.f/128.f);
    const float rstd1 = rsqrtf(sq * (1.f/128.f) - mean1*mean1 + 1e-5f);

    unsigned pk[8][2];
    #pragma unroll
    for (int mt = 0; mt < 8; ++mt) {
        pk[mt][0] = packbf(acc1[mt][0], acc1[mt][1]);
        pk[mt][1] = packbf(acc1[mt][2], acc1[mt][3]);
    }

    // ---------------- Layer 2: acc2 = W2'^T @ H1raw^T ----------------
    f4v acc2[8];
    #pragma unroll
    for (int mt = 0; mt < 8; ++mt) acc2[mt] = (f4v){0.f, 0.f, 0.f, 0.f};

    const int src0 = ((G & 1) << 5) + n16;
    const int src1 = src0 + 16;
    const bool hiG = (G >= 2);
    #pragma unroll
    for (int ks = 0; ks < 4; ++ks) {
        int r00 = __shfl((int)pk[2*ks][0],   src0, 64);
        int r01 = __shfl((int)pk[2*ks][1],   src0, 64);
        int r02 = __shfl((int)pk[2*ks][0],   src1, 64);
        int r03 = __shfl((int)pk[2*ks][1],   src1, 64);
        int r10 = __shfl((int)pk[2*ks+1][0], src0, 64);
        int r11 = __shfl((int)pk[2*ks+1][1], src0, 64);
        int r12 = __shfl((int)pk[2*ks+1][0], src1, 64);
        int r13 = __shfl((int)pk[2*ks+1][1], src1, 64);
        union { int u[4]; s8v v; } hb;
        hb.u[0] = hiG ? r10 : r00; hb.u[1] = hiG ? r11 : r01;
        hb.u[2] = hiG ? r12 : r02; hb.u[3] = hiG ? r13 : r03;
        s8v wfr[8];
        #pragma unroll
        for (int mt = 0; mt < 8; ++mt)
            wfr[mt] = *(const s8v*)&Ws[W2OFF + ((ks*8 + mt)*64 + lane) * 8];
        #pragma unroll
        for (int mt = 0; mt < 8; ++mt)
            acc2[mt] = __builtin_amdgcn_mfma_f32_16x16x32_bf16(wfr[mt], hb.v, acc2[mt], 0, 0, 0);
    }

    // ---------------- folded LN1 apply + LN2 stats ----------------
    float h2[8][4];
    float sm2 = 0.f, sq2 = 0.f;
    #pragma unroll
    for (int mt = 0; mt < 8; ++mt) {
        const int col = mt*16 + G*4;
        f4v s2l = *(const f4v*)&s2v[col];
        f4v bwl = *(const f4v*)&bwv[col];
        #pragma unroll
        for (int j = 0; j < 4; ++j) {
            float v = rstd1 * (acc2[mt][j] - mean1 * s2l[j]) + bwl[j];
            h2[mt][j] = v; sm2 += v; sq2 += v*v;
        }
    }
    sm2 += __shfl_xor(sm2, 16, 64); sm2 += __shfl_xor(sm2, 32, 64);
    sq2 += __shfl_xor(sq2, 16, 64); sq2 += __shfl_xor(sq2, 32, 64);
    const float mean2 = sm2 * (1.f/128.f);
    const float rstd2 = rsqrtf(sq2 * (1.f/128.f) - mean2*mean2 + 1e-5f);

    // ---------------- LN2 + ReLU + (FINE: add prefetched gather) + store ----
    if constexpr (FINE) {
        #pragma unroll
        for (int mt = 0; mt < 8; ++mt) {
            const int col = mt*16 + G*4;
            f4v g2l = *(const f4v*)&g2v[col];
            f4v b2l = *(const f4v*)&b2v[col];
            float z0 = fmaxf((h2[mt][0]-mean2)*rstd2*g2l[0] + b2l[0], 0.f);
            float z1 = fmaxf((h2[mt][1]-mean2)*rstd2*g2l[1] + b2l[1], 0.f);
            float z2 = fmaxf((h2[mt][2]-mean2)*rstd2*g2l[2] + b2l[2], 0.f);
            float z3 = fmaxf((h2[mt][3]-mean2)*rstd2*g2l[3] + b2l[3], 0.f);
            if (hasw) {
                z0 += bf2f(gv[mt].x); z1 += bf2f(gv[mt].y);
                z2 += bf2f(gv[mt].z); z3 += bf2f(gv[mt].w);
            }
            float4 o; o.x = z0; o.y = z1; o.z = z2; o.w = z3;
            *(float4*)(outF + (size_t)row * 128 + col) = o;
        }
    } else {
        #pragma unroll
        for (int mt = 0; mt < 8; ++mt) {
            const int col = mt*16 + G*4;
            f4v g2l = *(const f4v*)&g2v[col];
            f4v b2l = *(const f4v*)&b2v[col];
            ushort4 o;
            o.x = (unsigned short)f2bf(fmaxf((h2[mt][0]-mean2)*rstd2*g2l[0] + b2l[0], 0.f));
            o.y = (unsigned short)f2bf(fmaxf((h2[mt][1]-mean2)*rstd2*g2l[1] + b2l[1], 0.f));
            o.z = (unsigned short)f2bf(fmaxf((h2[mt][2]-mean2)*rstd2*g2l[2] + b2l[2], 0.f));
            o.w = (unsigned short)f2bf(fmaxf((h2[mt][3]-mean2)*rstd2*g2l[3] + b2l[3], 0.f));
            *(ushort4*)(outB + (size_t)row * 128 + col) = o;
        }
    }
}

extern "C" void kernel_launch(void* const* d_in, const int* in_sizes, int n_in,
                              void* d_out, int out_size, void* d_ws, size_t ws_size,
                              hipStream_t stream)
{
    const float* fcoarse = (const float*)d_in[0];
    const float* ffine   = (const float*)d_in[1];
    const float* w1c = (const float*)d_in[2];
    const float* g1c = (const float*)d_in[3];
    const float* b1c = (const float*)d_in[4];
    const float* w2c = (const float*)d_in[5];
    const float* g2c = (const float*)d_in[6];
    const float* b2c = (const float*)d_in[7];
    const float* w1f = (const float*)d_in[8];
    const float* g1f = (const float*)d_in[9];
    const float* b1f = (const float*)d_in[10];
    const float* w2f = (const float*)d_in[11];
    const float* g2f = (const float*)d_in[12];
    const float* b2f = (const float*)d_in[13];
    const int* nrow  = (const int*)d_in[14];
    const int* ncol  = (const int*)d_in[15];

    float* out = (float*)d_out;
    const int Mc = 32768, Mf = 131072;

    // ws: fcB 8MB | winner 512KB | packs 160KB | fold vecs 2KB
    unsigned short* fcB = (unsigned short*)d_ws;
    char* base = (char*)d_ws;
    int*   winner = (int*)(base + 8u*1024*1024);
    short* p1c = (short*)(base + 8u*1024*1024 + 512u*1024);
    short* p2c = p1c + 256*128;
    short* p1f = p2c + 128*128;
    short* p2f = p1f + 128*128;
    float* s2c = (float*)(p2f + 128*128);
    float* bwc = s2c + 128;
    float* s2f = bwc + 128;
    float* bwf = s2f + 128;

    // prep: pack weights + fold vectors + zero winner
    prep_kernel<<<170, 256, 0, stream>>>(w1c, w2c, g1c, b1c, w1f, w2f, g1f, b1f,
                                         p1c, p2c, p1f, p2f, s2c, bwc, s2f, bwf,
                                         winner);

    // coarse MLP (256 blocks of 128 rows) + winner resolution (512 blocks)
    mlp_mfma<256, false><<<512 + Mc/128, 512, 0, stream>>>(
        fcoarse, p1c, p2c, s2c, bwc, g2c, b2c,
        nullptr, fcB, nullptr, nullptr,
        nrow, ncol, winner, 512);

    // fine MLP + fused scatter -> out (1024 blocks of 128 rows)
    mlp_mfma<128, true><<<Mf/128, 512, 0, stream>>>(
        ffine, p1f, p2f, s2f, bwf, g2f, b2f,
        out, nullptr, winner, fcB,
        nullptr, nullptr, nullptr, 0);
}